// Round 9
// baseline (953.472 us; speedup 1.0000x reference)
//
#include <hip/hip_runtime.h>

#define NN 100000
#define NE 1600000
#define CH 128
#define NG 512
#define OUTC 11

// ---------------------------------------------------------------------------
// init: zero the atomic counter array (ws is poisoned 0xAA each call)
__global__ void init_kernel(int* __restrict__ cnt) {
    int i = blockIdx.x * 256 + threadIdx.x;
    if (i < NN) cnt[i] = 0;
}

// ---- exclusive scan of cnt[NN] -> colptr[NN+1] (3-kernel hierarchical) ----
__global__ void scan1_kernel(const int* __restrict__ cnt, int* __restrict__ excl,
                             int* __restrict__ bsum) {
    __shared__ int s[256];
    int t = threadIdx.x;
    int i = blockIdx.x * 256 + t;
    int v = (i < NN) ? cnt[i] : 0;
    s[t] = v;
    __syncthreads();
    #pragma unroll
    for (int off = 1; off < 256; off <<= 1) {
        int x = (t >= off) ? s[t - off] : 0;
        __syncthreads();
        s[t] += x;
        __syncthreads();
    }
    if (i < NN) excl[i] = s[t] - v;
    if (t == 255) bsum[blockIdx.x] = s[255];
}

#define SCAN_NB 391  // ceil(100000/256)

__global__ void scan2_kernel(const int* __restrict__ bsum, int* __restrict__ boff) {
    __shared__ int s[512];
    int t = threadIdx.x;
    int v = (t < SCAN_NB) ? bsum[t] : 0;
    s[t] = v;
    __syncthreads();
    #pragma unroll
    for (int off = 1; off < 512; off <<= 1) {
        int x = (t >= off) ? s[t - off] : 0;
        __syncthreads();
        s[t] += x;
        __syncthreads();
    }
    if (t < SCAN_NB) boff[t] = s[t] - v;
}

__global__ void scan3_kernel(const int* __restrict__ excl, const int* __restrict__ boff,
                             int* __restrict__ colptr) {
    int i = blockIdx.x * 256 + threadIdx.x;
    if (i < NN) colptr[i] = excl[i] + boff[i >> 8];
    if (i == 0) colptr[NN] = NE;
}

// scatter (atomic-free): csr[pos] = {src row, raw edge weight}
__global__ void scatter_kernel(const int* __restrict__ ei, const float* __restrict__ ew,
                               const int* __restrict__ colptr, const int* __restrict__ rankv,
                               int2* __restrict__ csr) {
    int e = blockIdx.x * 256 + threadIdx.x;   // grid is exactly NE/256
    int row = ei[e];
    int col = ei[NE + e];
    int pos = colptr[col] + rankv[e];
    csr[pos] = make_int2(row, __float_as_int(ew[e]));
}

// per-node: deg = sum of segment ew (contiguous, no atomics); dis = 1/sqrt(deg+1)
__global__ void deg_dis_kernel(const int* __restrict__ colptr, const int2* __restrict__ csr,
                               float* __restrict__ dis, float* __restrict__ selfw) {
    int i = blockIdx.x * 256 + threadIdx.x;
    if (i >= NN) return;
    int s = colptr[i], t = colptr[i + 1];
    float sum = 0.0f;
    for (int p = s; p < t; ++p) sum += __int_as_float(csr[p].y);
    float d = sum + 1.0f;
    float r = 1.0f / sqrtf(d);
    dis[i] = r;
    selfw[i] = r * r;
}

// per-node: csr[p].y <- dis[row] * ew * dis[col]  (in place)
__global__ void val_kernel(const int* __restrict__ colptr, const float* __restrict__ dis,
                           int2* __restrict__ csr) {
    int i = blockIdx.x * 256 + threadIdx.x;
    if (i >= NN) return;
    float dn = dis[i];
    int s = colptr[i], t = colptr[i + 1];
    for (int p = s; p < t; ++p) {
        int2 v = csr[p];
        csr[p].y = __float_as_int(dis[v.x] * __int_as_float(v.y) * dn);
    }
}

// graph boundaries in sorted batch: starts[g] = lower_bound(batch, g)
__global__ void starts_kernel(const int* __restrict__ batch, int* __restrict__ starts) {
    int g = blockIdx.x * 256 + threadIdx.x;
    if (g > NG) return;
    int lo = 0, hi = NN;
    while (lo < hi) {
        int mid = (lo + hi) >> 1;
        if (batch[mid] < g) lo = mid + 1; else hi = mid;
    }
    starts[g] = lo;
}

// ---------------------------------------------------------------------------
// f32 GEMM tile body: C[M,128] = A[M,128] @ W[128,128]. 128-row tile, 256 thr,
// 8x8 register micro-tile, K staged in panels of 32 (A transposed in LDS).
#define BM 128
#define BK 32

__device__ __forceinline__ void gemm_tile_body(const float* __restrict__ A,
                                               const float* __restrict__ W,
                                               float* __restrict__ C, int M, int blk) {
    __shared__ float At[BK][132];   // [k][row], padded stride
    __shared__ float Wp[BK][CH];    // [k][col]
    const int tid = threadIdx.x;
    const int row0 = blk * BM;
    const int tc = (tid & 15) * 8;  // col start (16 thread-cols x 8)
    const int tr = (tid >> 4) * 8;  // row start (16 thread-rows x 8)

    float acc[8][8];
    #pragma unroll
    for (int i = 0; i < 8; ++i)
        #pragma unroll
        for (int j = 0; j < 8; ++j) acc[i][j] = 0.0f;

    for (int kk = 0; kk < CH; kk += BK) {
        #pragma unroll
        for (int i = 0; i < 4; ++i) {
            int f4 = i * 256 + tid;
            int k = f4 >> 5;
            int c4 = (f4 & 31) * 4;
            *reinterpret_cast<float4*>(&Wp[k][c4]) =
                *reinterpret_cast<const float4*>(&W[(kk + k) * CH + c4]);
        }
        #pragma unroll
        for (int i = 0; i < 4; ++i) {
            int f4 = i * 256 + tid;
            int r = f4 >> 3;
            int kp = (f4 & 7) * 4;
            float4 a4 = make_float4(0.f, 0.f, 0.f, 0.f);
            int grow = row0 + r;
            if (grow < M)
                a4 = *reinterpret_cast<const float4*>(&A[grow * CH + kk + kp]);
            At[kp + 0][r] = a4.x;
            At[kp + 1][r] = a4.y;
            At[kp + 2][r] = a4.z;
            At[kp + 3][r] = a4.w;
        }
        __syncthreads();
        #pragma unroll 4
        for (int k = 0; k < BK; ++k) {
            float a[8], w[8];
            *reinterpret_cast<float4*>(&a[0]) = *reinterpret_cast<const float4*>(&At[k][tr]);
            *reinterpret_cast<float4*>(&a[4]) = *reinterpret_cast<const float4*>(&At[k][tr + 4]);
            *reinterpret_cast<float4*>(&w[0]) = *reinterpret_cast<const float4*>(&Wp[k][tc]);
            *reinterpret_cast<float4*>(&w[4]) = *reinterpret_cast<const float4*>(&Wp[k][tc + 4]);
            #pragma unroll
            for (int i = 0; i < 8; ++i)
                #pragma unroll
                for (int j = 0; j < 8; ++j)
                    acc[i][j] = fmaf(a[i], w[j], acc[i][j]);
        }
        __syncthreads();
    }
    #pragma unroll
    for (int i = 0; i < 8; ++i) {
        int grow = row0 + tr + i;
        if (grow < M) {
            float4 v0 = make_float4(acc[i][0], acc[i][1], acc[i][2], acc[i][3]);
            float4 v1 = make_float4(acc[i][4], acc[i][5], acc[i][6], acc[i][7]);
            *reinterpret_cast<float4*>(&C[grow * CH + tc]) = v0;
            *reinterpret_cast<float4*>(&C[grow * CH + tc + 4]) = v1;
        }
    }
}

__global__ __launch_bounds__(256, 4) void gemm_kernel(const float* __restrict__ A,
                                                      const float* __restrict__ W,
                                                      float* __restrict__ C, int M) {
    gemm_tile_body(A, W, C, M, blockIdx.x);
}

// fused: GEMM layer-1 (every 9th block) overlapped with the edge-rank atomic
// pass (other blocks).
#define FUSE_NB 7032  // 782 gemm blocks + 6250 rank blocks

__global__ __launch_bounds__(256, 4) void gemm_rank_kernel(const float* __restrict__ A,
                                                           const float* __restrict__ W,
                                                           float* __restrict__ C, int M,
                                                           const int* __restrict__ ei,
                                                           int* __restrict__ cnt,
                                                           int* __restrict__ rankv) {
    int bid = blockIdx.x;
    if (bid % 9 == 0) {
        gemm_tile_body(A, W, C, M, bid / 9);
    } else {
        int r = bid - 1 - bid / 9;          // rank-block index 0..6249
        int e = r * 256 + threadIdx.x;      // exact: 6250*256 == NE
        int col = ei[NE + e];
        rankv[e] = atomicAdd(&cnt[col], 1);
    }
}

// ---------------------------------------------------------------------------
// channel-chunked aggregation: blockIdx.y selects a 32-channel chunk (12.8 MB
// slice -> L3-resident, 3.2x per-XCD L2). One WAVE per node; 8 edge-slots x
// 8 lanes x float4 => 8 independent 128B gathers in flight. Slot-reduce via
// 3x shfl_xor, then slot 0 adds self+bias, relu, stores 128B.
#define CHUNK 32

__global__ __launch_bounds__(256) void agg_kernel(const float* __restrict__ hW,
                                                  const int* __restrict__ colptr,
                                                  const int2* __restrict__ csr,
                                                  const float* __restrict__ selfw,
                                                  const float* __restrict__ bias,
                                                  float* __restrict__ out) {
    const int wave = threadIdx.x >> 6;
    const int lane = threadIdx.x & 63;
    const int node = blockIdx.x * 4 + wave;          // grid.x = NN/4 exact
    const int slot = lane >> 3;                      // 0..7 edge slot
    const int c = blockIdx.y * CHUNK + (lane & 7) * 4;  // this lane's 4 channels

    float ax = 0.0f, ay = 0.0f, az = 0.0f, aw = 0.0f;
    const int e1 = colptr[node + 1];
    for (int e = colptr[node] + slot; e < e1; e += 8) {
        int2 p = csr[e];
        float v = __int_as_float(p.y);
        float4 h = *reinterpret_cast<const float4*>(&hW[(size_t)p.x * CH + c]);
        ax = fmaf(v, h.x, ax); ay = fmaf(v, h.y, ay);
        az = fmaf(v, h.z, az); aw = fmaf(v, h.w, aw);
    }
    // reduce across the 8 slots (lanes differing in bits 3..5)
    #pragma unroll
    for (int m = 8; m < 64; m <<= 1) {
        ax += __shfl_xor(ax, m);
        ay += __shfl_xor(ay, m);
        az += __shfl_xor(az, m);
        aw += __shfl_xor(aw, m);
    }
    if (slot == 0) {
        const float sw = selfw[node];
        const float4 sv = *reinterpret_cast<const float4*>(&hW[(size_t)node * CH + c]);
        const float4 b = *reinterpret_cast<const float4*>(&bias[c]);
        float4 o;
        o.x = fmaxf(fmaf(sw, sv.x, ax) + b.x, 0.0f);
        o.y = fmaxf(fmaf(sw, sv.y, ay) + b.y, 0.0f);
        o.z = fmaxf(fmaf(sw, sv.z, az) + b.z, 0.0f);
        o.w = fmaxf(fmaf(sw, sv.w, aw) + b.w, 0.0f);
        *reinterpret_cast<float4*>(&out[(size_t)node * CH + c]) = o;
    }
}

// ---------------------------------------------------------------------------
// mean pool per graph (batch sorted -> contiguous node ranges)
__global__ __launch_bounds__(128) void pool_kernel(const float* __restrict__ feat,
                                                   const int* __restrict__ starts,
                                                   float* __restrict__ pooled) {
    int g = blockIdx.x;
    int c = threadIdx.x;
    int s = starts[g], e = starts[g + 1];
    float acc = 0.0f;
    for (int n = s; n < e; ++n) acc += feat[(size_t)n * CH + c];
    pooled[g * CH + c] = acc / fmaxf((float)(e - s), 1.0f);
}

// final FC: out[g,o] = pooled[g,:] @ fcW[:,o] + fcb[o]
__global__ __launch_bounds__(192) void fc_kernel(const float* __restrict__ pooled,
                                                 const float* __restrict__ fcW,
                                                 const float* __restrict__ fcb,
                                                 float* __restrict__ out) {
    int g = blockIdx.x * 16 + threadIdx.x / 12;
    int o = threadIdx.x % 12;
    if (g >= NG || o >= OUTC) return;
    float acc = fcb[o];
    #pragma unroll 8
    for (int c = 0; c < CH; ++c)
        acc = fmaf(pooled[g * CH + c], fcW[c * OUTC + o], acc);
    out[g * OUTC + o] = acc;
}

// ---------------------------------------------------------------------------
extern "C" void kernel_launch(void* const* d_in, const int* in_sizes, int n_in,
                              void* d_out, int out_size, void* d_ws, size_t ws_size,
                              hipStream_t stream) {
    const float* x      = (const float*)d_in[0];
    const int*   ei     = (const int*)d_in[1];
    const int*   batch  = (const int*)d_in[2];
    const float* ew     = (const float*)d_in[3];
    const float* W1     = (const float*)d_in[4];
    const float* b1     = (const float*)d_in[5];
    const float* W2     = (const float*)d_in[6];
    const float* b2     = (const float*)d_in[7];
    const float* W3     = (const float*)d_in[8];
    const float* b3     = (const float*)d_in[9];
    const float* fcW    = (const float*)d_in[10];
    const float* fcb    = (const float*)d_in[11];
    float* out = (float*)d_out;

    // workspace carve-up (256B aligned)
    char* p = (char*)d_ws;
    auto alloc = [&](size_t bytes) {
        void* r = (void*)p;
        p += (bytes + 255) & ~(size_t)255;
        return r;
    };
    float* featA   = (float*)alloc((size_t)NN * CH * 4);
    float* featB   = (float*)alloc((size_t)NN * CH * 4);
    int*   cnt     = (int*)alloc(NN * 4);
    int*   rankv   = (int*)alloc((size_t)NE * 4);
    int*   excl    = (int*)alloc(NN * 4);
    int*   bsum    = (int*)alloc(SCAN_NB * 4);
    int*   boff    = (int*)alloc(SCAN_NB * 4);
    int*   colptr  = (int*)alloc((NN + 1) * 4);
    int2*  csr     = (int2*)alloc((size_t)NE * 8);
    float* dis     = (float*)alloc(NN * 4);
    float* selfw   = (float*)alloc(NN * 4);
    int*   starts  = (int*)alloc((NG + 1) * 4);
    float* pooled  = (float*)alloc((size_t)NG * CH * 4);

    const int nb_nodes = (NN + 255) / 256;      // 391
    const int nb_edges = (NE + 255) / 256;      // 6250
    const int nb_gemm  = (NN + BM - 1) / BM;    // 782
    const dim3 gr_agg(NN / 4, CH / CHUNK);      // 25000 x 4 passes

    // preprocessing (reused by all 3 layers); gemm1 overlapped with rank pass
    init_kernel<<<nb_nodes, 256, 0, stream>>>(cnt);
    gemm_rank_kernel<<<FUSE_NB, 256, 0, stream>>>(x, W1, featA, NN, ei, cnt, rankv);
    scan1_kernel<<<SCAN_NB, 256, 0, stream>>>(cnt, excl, bsum);
    scan2_kernel<<<1, 512, 0, stream>>>(bsum, boff);
    scan3_kernel<<<nb_nodes, 256, 0, stream>>>(excl, boff, colptr);
    scatter_kernel<<<nb_edges, 256, 0, stream>>>(ei, ew, colptr, rankv, csr);
    deg_dis_kernel<<<nb_nodes, 256, 0, stream>>>(colptr, csr, dis, selfw);
    val_kernel<<<nb_nodes, 256, 0, stream>>>(colptr, dis, csr);
    starts_kernel<<<3, 256, 0, stream>>>(batch, starts);

    // layer 1 aggregation (gemm1 already done in fused kernel)
    agg_kernel<<<gr_agg, 256, 0, stream>>>(featA, colptr, csr, selfw, b1, featB);
    // layer 2
    gemm_kernel<<<nb_gemm, 256, 0, stream>>>(featB, W2, featA, NN);
    agg_kernel<<<gr_agg, 256, 0, stream>>>(featA, colptr, csr, selfw, b2, featB);
    // layer 3
    gemm_kernel<<<nb_gemm, 256, 0, stream>>>(featB, W3, featA, NN);
    agg_kernel<<<gr_agg, 256, 0, stream>>>(featA, colptr, csr, selfw, b3, featB);

    // pool + fc
    pool_kernel<<<NG, 128, 0, stream>>>(featB, starts, pooled);
    fc_kernel<<<(NG + 15) / 16, 192, 0, stream>>>(pooled, fcW, fcb, out);
}

// Round 11
// 674.543 us; speedup vs baseline: 1.4135x; 1.4135x over previous
//
#include <hip/hip_runtime.h>
#include <hip/hip_fp16.h>

#define NN 100000
#define NE 1600000
#define CH 128
#define NG 512
#define OUTC 11

// ---------------------------------------------------------------------------
__global__ void init_kernel(int* __restrict__ cnt) {
    int i = blockIdx.x * 256 + threadIdx.x;
    if (i < NN) cnt[i] = 0;
}

// ---- exclusive scan of cnt[NN] -> colptr[NN+1] (3-kernel hierarchical) ----
__global__ void scan1_kernel(const int* __restrict__ cnt, int* __restrict__ excl,
                             int* __restrict__ bsum) {
    __shared__ int s[256];
    int t = threadIdx.x;
    int i = blockIdx.x * 256 + t;
    int v = (i < NN) ? cnt[i] : 0;
    s[t] = v;
    __syncthreads();
    #pragma unroll
    for (int off = 1; off < 256; off <<= 1) {
        int x = (t >= off) ? s[t - off] : 0;
        __syncthreads();
        s[t] += x;
        __syncthreads();
    }
    if (i < NN) excl[i] = s[t] - v;
    if (t == 255) bsum[blockIdx.x] = s[255];
}

#define SCAN_NB 391  // ceil(100000/256)

__global__ void scan2_kernel(const int* __restrict__ bsum, int* __restrict__ boff) {
    __shared__ int s[512];
    int t = threadIdx.x;
    int v = (t < SCAN_NB) ? bsum[t] : 0;
    s[t] = v;
    __syncthreads();
    #pragma unroll
    for (int off = 1; off < 512; off <<= 1) {
        int x = (t >= off) ? s[t - off] : 0;
        __syncthreads();
        s[t] += x;
        __syncthreads();
    }
    if (t < SCAN_NB) boff[t] = s[t] - v;
}

__global__ void scan3_kernel(const int* __restrict__ excl, const int* __restrict__ boff,
                             int* __restrict__ colptr) {
    int i = blockIdx.x * 256 + threadIdx.x;
    if (i < NN) colptr[i] = excl[i] + boff[i >> 8];
    if (i == 0) colptr[NN] = NE;
}

// scatter (atomic-free): csr[pos] = {src row, raw edge weight}
__global__ void scatter_kernel(const int* __restrict__ ei, const float* __restrict__ ew,
                               const int* __restrict__ colptr, const int* __restrict__ rankv,
                               int2* __restrict__ csr) {
    int e = blockIdx.x * 256 + threadIdx.x;   // grid is exactly NE/256
    int row = ei[e];
    int col = ei[NE + e];
    int pos = colptr[col] + rankv[e];
    csr[pos] = make_int2(row, __float_as_int(ew[e]));
}

// per-node: deg = sum of segment ew; dis = 1/sqrt(deg+1)  (all f32 exact)
__global__ void deg_dis_kernel(const int* __restrict__ colptr, const int2* __restrict__ csr,
                               float* __restrict__ dis, float* __restrict__ selfw) {
    int i = blockIdx.x * 256 + threadIdx.x;
    if (i >= NN) return;
    int s = colptr[i], t = colptr[i + 1];
    float sum = 0.0f;
    for (int p = s; p < t; ++p) sum += __int_as_float(csr[p].y);
    float d = sum + 1.0f;
    float r = 1.0f / sqrtf(d);
    dis[i] = r;
    selfw[i] = r * r;
}

// per-node: csr[p].y <- dis[row] * ew * dis[col]  (in place, f32 exact)
__global__ void val_kernel(const int* __restrict__ colptr, const float* __restrict__ dis,
                           int2* __restrict__ csr) {
    int i = blockIdx.x * 256 + threadIdx.x;
    if (i >= NN) return;
    float dn = dis[i];
    int s = colptr[i], t = colptr[i + 1];
    for (int p = s; p < t; ++p) {
        int2 v = csr[p];
        csr[p].y = __float_as_int(dis[v.x] * __int_as_float(v.y) * dn);
    }
}

// graph boundaries in sorted batch
__global__ void starts_kernel(const int* __restrict__ batch, int* __restrict__ starts) {
    int g = blockIdx.x * 256 + threadIdx.x;
    if (g > NG) return;
    int lo = 0, hi = NN;
    while (lo < hi) {
        int mid = (lo + hi) >> 1;
        if (batch[mid] < g) lo = mid + 1; else hi = mid;
    }
    starts[g] = lo;
}

// ---------------------------------------------------------------------------
// GEMM: C[M,128](fp16) = A[M,128] @ W[128,128](f32). A is f32 or fp16
// (templated loader -> f32 in LDS). f32 accumulate, fp16 store.
#define BM 128
#define BK 32

template <typename TA>
__device__ __forceinline__ void gemm_tile_body(const TA* __restrict__ A,
                                               const float* __restrict__ W,
                                               __half* __restrict__ C, int M, int blk) {
    __shared__ float At[BK][132];   // [k][row], padded stride
    __shared__ float Wp[BK][CH];    // [k][col]
    const int tid = threadIdx.x;
    const int row0 = blk * BM;
    const int tc = (tid & 15) * 8;
    const int tr = (tid >> 4) * 8;

    float acc[8][8];
    #pragma unroll
    for (int i = 0; i < 8; ++i)
        #pragma unroll
        for (int j = 0; j < 8; ++j) acc[i][j] = 0.0f;

    for (int kk = 0; kk < CH; kk += BK) {
        #pragma unroll
        for (int i = 0; i < 4; ++i) {
            int f4 = i * 256 + tid;
            int k = f4 >> 5;
            int c4 = (f4 & 31) * 4;
            *reinterpret_cast<float4*>(&Wp[k][c4]) =
                *reinterpret_cast<const float4*>(&W[(kk + k) * CH + c4]);
        }
        #pragma unroll
        for (int i = 0; i < 4; ++i) {
            int f4 = i * 256 + tid;
            int r = f4 >> 3;
            int kp = (f4 & 7) * 4;
            int grow = row0 + r;
            float a0 = 0.f, a1 = 0.f, a2 = 0.f, a3 = 0.f;
            if (grow < M) {
                if constexpr (sizeof(TA) == 4) {
                    float4 a4 = *reinterpret_cast<const float4*>(&A[(size_t)grow * CH + kk + kp]);
                    a0 = a4.x; a1 = a4.y; a2 = a4.z; a3 = a4.w;
                } else {
                    float2 raw = *reinterpret_cast<const float2*>(&A[(size_t)grow * CH + kk + kp]);
                    const __half* hp = reinterpret_cast<const __half*>(&raw);
                    a0 = __half2float(hp[0]); a1 = __half2float(hp[1]);
                    a2 = __half2float(hp[2]); a3 = __half2float(hp[3]);
                }
            }
            At[kp + 0][r] = a0;
            At[kp + 1][r] = a1;
            At[kp + 2][r] = a2;
            At[kp + 3][r] = a3;
        }
        __syncthreads();
        #pragma unroll 4
        for (int k = 0; k < BK; ++k) {
            float a[8], w[8];
            *reinterpret_cast<float4*>(&a[0]) = *reinterpret_cast<const float4*>(&At[k][tr]);
            *reinterpret_cast<float4*>(&a[4]) = *reinterpret_cast<const float4*>(&At[k][tr + 4]);
            *reinterpret_cast<float4*>(&w[0]) = *reinterpret_cast<const float4*>(&Wp[k][tc]);
            *reinterpret_cast<float4*>(&w[4]) = *reinterpret_cast<const float4*>(&Wp[k][tc + 4]);
            #pragma unroll
            for (int i = 0; i < 8; ++i)
                #pragma unroll
                for (int j = 0; j < 8; ++j)
                    acc[i][j] = fmaf(a[i], w[j], acc[i][j]);
        }
        __syncthreads();
    }
    #pragma unroll
    for (int i = 0; i < 8; ++i) {
        int grow = row0 + tr + i;
        if (grow < M) {
            __half hb[8];
            #pragma unroll
            for (int j = 0; j < 8; ++j) hb[j] = __float2half(acc[i][j]);
            *reinterpret_cast<float4*>(&C[(size_t)grow * CH + tc]) =
                *reinterpret_cast<float4*>(hb);
        }
    }
}

__global__ __launch_bounds__(256, 4) void gemm_h_kernel(const __half* __restrict__ A,
                                                        const float* __restrict__ W,
                                                        __half* __restrict__ C, int M) {
    gemm_tile_body<__half>(A, W, C, M, blockIdx.x);
}

// fused: layer-1 GEMM (f32 A) overlapped with the edge-rank atomic pass
#define FUSE_NB 7032  // 782 gemm blocks + 6250 rank blocks

__global__ __launch_bounds__(256, 4) void gemm_rank_kernel(const float* __restrict__ A,
                                                           const float* __restrict__ W,
                                                           __half* __restrict__ C, int M,
                                                           const int* __restrict__ ei,
                                                           int* __restrict__ cnt,
                                                           int* __restrict__ rankv) {
    int bid = blockIdx.x;
    if (bid % 9 == 0) {
        gemm_tile_body<float>(A, W, C, M, bid / 9);
    } else {
        int r = bid - 1 - bid / 9;          // rank-block index 0..6249
        int e = r * 256 + threadIdx.x;      // exact: 6250*256 == NE
        int col = ei[NE + e];
        rankv[e] = atomicAdd(&cnt[col], 1);
    }
}

// ---------------------------------------------------------------------------
// aggregation (round-8 structure, fp16 payload): HALF-wave per node, 8B/lane
// covers the 256B fp16 row in one dwordx2, unroll-2 for MLP. f32 accumulate,
// fp16 store. 8 nodes per 256-thread block.
__global__ __launch_bounds__(256) void agg_kernel(const __half* __restrict__ hW,
                                                  const int* __restrict__ colptr,
                                                  const int2* __restrict__ csr,
                                                  const float* __restrict__ selfw,
                                                  const float* __restrict__ bias,
                                                  __half* __restrict__ out) {
    const int sub = threadIdx.x >> 5;
    const int l = threadIdx.x & 31;
    const int node = blockIdx.x * 8 + sub;     // grid = NN/8 exact
    const int c0 = l * 4;

    float ax, ay, az, aw;
    {
        const float sw = selfw[node];
        float2 raw = *reinterpret_cast<const float2*>(&hW[(size_t)node * CH + c0]);
        const __half* hp = reinterpret_cast<const __half*>(&raw);
        ax = sw * __half2float(hp[0]); ay = sw * __half2float(hp[1]);
        az = sw * __half2float(hp[2]); aw = sw * __half2float(hp[3]);
    }

    int e = colptr[node];
    const int e1 = colptr[node + 1];
    for (; e + 1 < e1; e += 2) {
        int2 p0 = csr[e];
        int2 p1 = csr[e + 1];
        float2 r0 = *reinterpret_cast<const float2*>(&hW[(size_t)p0.x * CH + c0]);
        float2 r1 = *reinterpret_cast<const float2*>(&hW[(size_t)p1.x * CH + c0]);
        float v0 = __int_as_float(p0.y);
        float v1 = __int_as_float(p1.y);
        const __half* h0 = reinterpret_cast<const __half*>(&r0);
        const __half* h1 = reinterpret_cast<const __half*>(&r1);
        ax = fmaf(v0, __half2float(h0[0]), ax); ay = fmaf(v0, __half2float(h0[1]), ay);
        az = fmaf(v0, __half2float(h0[2]), az); aw = fmaf(v0, __half2float(h0[3]), aw);
        ax = fmaf(v1, __half2float(h1[0]), ax); ay = fmaf(v1, __half2float(h1[1]), ay);
        az = fmaf(v1, __half2float(h1[2]), az); aw = fmaf(v1, __half2float(h1[3]), aw);
    }
    if (e < e1) {
        int2 p0 = csr[e];
        float2 r0 = *reinterpret_cast<const float2*>(&hW[(size_t)p0.x * CH + c0]);
        float v0 = __int_as_float(p0.y);
        const __half* h0 = reinterpret_cast<const __half*>(&r0);
        ax = fmaf(v0, __half2float(h0[0]), ax); ay = fmaf(v0, __half2float(h0[1]), ay);
        az = fmaf(v0, __half2float(h0[2]), az); aw = fmaf(v0, __half2float(h0[3]), aw);
    }
    const float4 b = *reinterpret_cast<const float4*>(&bias[c0]);
    __half o[4];
    o[0] = __float2half(fmaxf(ax + b.x, 0.0f));
    o[1] = __float2half(fmaxf(ay + b.y, 0.0f));
    o[2] = __float2half(fmaxf(az + b.z, 0.0f));
    o[3] = __float2half(fmaxf(aw + b.w, 0.0f));
    *reinterpret_cast<float2*>(&out[(size_t)node * CH + c0]) = *reinterpret_cast<float2*>(o);
}

// ---------------------------------------------------------------------------
// mean pool per graph (fp16 feat -> f32 accumulate -> f32 pooled)
__global__ __launch_bounds__(128) void pool_kernel(const __half* __restrict__ feat,
                                                   const int* __restrict__ starts,
                                                   float* __restrict__ pooled) {
    int g = blockIdx.x;
    int c = threadIdx.x;
    int s = starts[g], e = starts[g + 1];
    float acc = 0.0f;
    for (int n = s; n < e; ++n) acc += __half2float(feat[(size_t)n * CH + c]);
    pooled[g * CH + c] = acc / fmaxf((float)(e - s), 1.0f);
}

// final FC
__global__ __launch_bounds__(192) void fc_kernel(const float* __restrict__ pooled,
                                                 const float* __restrict__ fcW,
                                                 const float* __restrict__ fcb,
                                                 float* __restrict__ out) {
    int g = blockIdx.x * 16 + threadIdx.x / 12;
    int o = threadIdx.x % 12;
    if (g >= NG || o >= OUTC) return;
    float acc = fcb[o];
    #pragma unroll 8
    for (int c = 0; c < CH; ++c)
        acc = fmaf(pooled[g * CH + c], fcW[c * OUTC + o], acc);
    out[g * OUTC + o] = acc;
}

// ---------------------------------------------------------------------------
extern "C" void kernel_launch(void* const* d_in, const int* in_sizes, int n_in,
                              void* d_out, int out_size, void* d_ws, size_t ws_size,
                              hipStream_t stream) {
    const float* x      = (const float*)d_in[0];
    const int*   ei     = (const int*)d_in[1];
    const int*   batch  = (const int*)d_in[2];
    const float* ew     = (const float*)d_in[3];
    const float* W1     = (const float*)d_in[4];
    const float* b1     = (const float*)d_in[5];
    const float* W2     = (const float*)d_in[6];
    const float* b2     = (const float*)d_in[7];
    const float* W3     = (const float*)d_in[8];
    const float* b3     = (const float*)d_in[9];
    const float* fcW    = (const float*)d_in[10];
    const float* fcb    = (const float*)d_in[11];
    float* out = (float*)d_out;

    // workspace carve-up (256B aligned)
    char* p = (char*)d_ws;
    auto alloc = [&](size_t bytes) {
        void* r = (void*)p;
        p += (bytes + 255) & ~(size_t)255;
        return r;
    };
    __half* featA  = (__half*)alloc((size_t)NN * CH * 2);
    __half* featB  = (__half*)alloc((size_t)NN * CH * 2);
    int*   cnt     = (int*)alloc(NN * 4);
    int*   rankv   = (int*)alloc((size_t)NE * 4);
    int*   excl    = (int*)alloc(NN * 4);
    int*   bsum    = (int*)alloc(SCAN_NB * 4);
    int*   boff    = (int*)alloc(SCAN_NB * 4);
    int*   colptr  = (int*)alloc((NN + 1) * 4);
    int2*  csr     = (int2*)alloc((size_t)NE * 8);
    float* dis     = (float*)alloc(NN * 4);
    float* selfw   = (float*)alloc(NN * 4);
    int*   starts  = (int*)alloc((NG + 1) * 4);
    float* pooled  = (float*)alloc((size_t)NG * CH * 4);

    const int nb_nodes = (NN + 255) / 256;      // 391
    const int nb_edges = (NE + 255) / 256;      // 6250
    const int nb_gemm  = (NN + BM - 1) / BM;    // 782
    const int nb_agg   = NN / 8;                // 12500

    // preprocessing (reused by all 3 layers); gemm1 overlapped with rank pass
    init_kernel<<<nb_nodes, 256, 0, stream>>>(cnt);
    gemm_rank_kernel<<<FUSE_NB, 256, 0, stream>>>(x, W1, featA, NN, ei, cnt, rankv);
    scan1_kernel<<<SCAN_NB, 256, 0, stream>>>(cnt, excl, bsum);
    scan2_kernel<<<1, 512, 0, stream>>>(bsum, boff);
    scan3_kernel<<<nb_nodes, 256, 0, stream>>>(excl, boff, colptr);
    scatter_kernel<<<nb_edges, 256, 0, stream>>>(ei, ew, colptr, rankv, csr);
    deg_dis_kernel<<<nb_nodes, 256, 0, stream>>>(colptr, csr, dis, selfw);
    val_kernel<<<nb_nodes, 256, 0, stream>>>(colptr, dis, csr);
    starts_kernel<<<3, 256, 0, stream>>>(batch, starts);

    // layer 1 aggregation (gemm1 already done in fused kernel)
    agg_kernel<<<nb_agg, 256, 0, stream>>>(featA, colptr, csr, selfw, b1, featB);
    // layer 2
    gemm_h_kernel<<<nb_gemm, 256, 0, stream>>>(featB, W2, featA, NN);
    agg_kernel<<<nb_agg, 256, 0, stream>>>(featA, colptr, csr, selfw, b2, featB);
    // layer 3
    gemm_h_kernel<<<nb_gemm, 256, 0, stream>>>(featB, W3, featA, NN);
    agg_kernel<<<nb_agg, 256, 0, stream>>>(featA, colptr, csr, selfw, b3, featB);

    // pool + fc
    pool_kernel<<<NG, 128, 0, stream>>>(featB, starts, pooled);
    fc_kernel<<<(NG + 15) / 16, 192, 0, stream>>>(pooled, fcW, fcb, out);
}

// Round 13
// 656.440 us; speedup vs baseline: 1.4525x; 1.0276x over previous
//
#include <hip/hip_runtime.h>
#include <hip/hip_fp16.h>

#define NN 100000
#define NE 1600000
#define CH 128
#define NG 512
#define OUTC 11

// ---------------------------------------------------------------------------
__global__ void init_kernel(int* __restrict__ cnt) {
    int i = blockIdx.x * 256 + threadIdx.x;
    if (i < NN) cnt[i] = 0;
}

// ---- exclusive scan of cnt[NN] -> colptr[NN+1] (3-kernel hierarchical) ----
__global__ void scan1_kernel(const int* __restrict__ cnt, int* __restrict__ excl,
                             int* __restrict__ bsum) {
    __shared__ int s[256];
    int t = threadIdx.x;
    int i = blockIdx.x * 256 + t;
    int v = (i < NN) ? cnt[i] : 0;
    s[t] = v;
    __syncthreads();
    #pragma unroll
    for (int off = 1; off < 256; off <<= 1) {
        int x = (t >= off) ? s[t - off] : 0;
        __syncthreads();
        s[t] += x;
        __syncthreads();
    }
    if (i < NN) excl[i] = s[t] - v;
    if (t == 255) bsum[blockIdx.x] = s[255];
}

#define SCAN_NB 391  // ceil(100000/256)

__global__ void scan2_kernel(const int* __restrict__ bsum, int* __restrict__ boff) {
    __shared__ int s[512];
    int t = threadIdx.x;
    int v = (t < SCAN_NB) ? bsum[t] : 0;
    s[t] = v;
    __syncthreads();
    #pragma unroll
    for (int off = 1; off < 512; off <<= 1) {
        int x = (t >= off) ? s[t - off] : 0;
        __syncthreads();
        s[t] += x;
        __syncthreads();
    }
    if (t < SCAN_NB) boff[t] = s[t] - v;
}

__global__ void scan3_kernel(const int* __restrict__ excl, const int* __restrict__ boff,
                             int* __restrict__ colptr) {
    int i = blockIdx.x * 256 + threadIdx.x;
    if (i < NN) colptr[i] = excl[i] + boff[i >> 8];
    if (i == 0) colptr[NN] = NE;
}

// scatter (atomic-free): csr[pos] = {src row, raw edge weight}
__global__ void scatter_kernel(const int* __restrict__ ei, const float* __restrict__ ew,
                               const int* __restrict__ colptr, const int* __restrict__ rankv,
                               int2* __restrict__ csr) {
    int e = blockIdx.x * 256 + threadIdx.x;
    int row = ei[e];
    int col = ei[NE + e];
    int pos = colptr[col] + rankv[e];
    csr[pos] = make_int2(row, __float_as_int(ew[e]));
}

// per-node: deg = segment sum of ew; dis = 1/sqrt(deg+1)  (f32 exact)
__global__ void deg_dis_kernel(const int* __restrict__ colptr, const int2* __restrict__ csr,
                               float* __restrict__ dis, float* __restrict__ selfw) {
    int i = blockIdx.x * 256 + threadIdx.x;
    if (i >= NN) return;
    int s = colptr[i], t = colptr[i + 1];
    float sum = 0.0f;
    for (int p = s; p < t; ++p) sum += __int_as_float(csr[p].y);
    float d = sum + 1.0f;
    float r = 1.0f / sqrtf(d);
    dis[i] = r;
    selfw[i] = r * r;
}

// per-node: csr[p].y <- dis[row] * ew * dis[col]
__global__ void val_kernel(const int* __restrict__ colptr, const float* __restrict__ dis,
                           int2* __restrict__ csr) {
    int i = blockIdx.x * 256 + threadIdx.x;
    if (i >= NN) return;
    float dn = dis[i];
    int s = colptr[i], t = colptr[i + 1];
    for (int p = s; p < t; ++p) {
        int2 v = csr[p];
        csr[p].y = __float_as_int(dis[v.x] * __int_as_float(v.y) * dn);
    }
}

// graph boundaries in sorted batch
__global__ void starts_kernel(const int* __restrict__ batch, int* __restrict__ starts) {
    int g = blockIdx.x * 256 + threadIdx.x;
    if (g > NG) return;
    int lo = 0, hi = NN;
    while (lo < hi) {
        int mid = (lo + hi) >> 1;
        if (batch[mid] < g) lo = mid + 1; else hi = mid;
    }
    starts[g] = lo;
}

// ---------------------------------------------------------------------------
// GEMM: C[M,128](fp16) = A[M,128] @ W[128,128](f32). A f32 or fp16 (templated
// loader -> f32 in LDS). f32 accumulate, fp16 store. BK=16 keeps LDS at
// ~16.6KB so the LDS-free rank blocks in the fused kernel reach the 8-block/CU
// thread cap (round-11 profile: 33KB capped occupancy at 28.8%).
// K-accumulation order identical to BK=32 -> bit-identical results.
#define BM 128
#define BK 16

template <typename TA>
__device__ __forceinline__ void gemm_tile_body(const TA* __restrict__ A,
                                               const float* __restrict__ W,
                                               __half* __restrict__ C, int M, int blk) {
    __shared__ float At[BK][132];   // [k][row], padded stride (528B, 16B-aligned)
    __shared__ float Wp[BK][CH];    // [k][col]
    const int tid = threadIdx.x;
    const int row0 = blk * BM;
    const int tc = (tid & 15) * 8;
    const int tr = (tid >> 4) * 8;

    float acc[8][8];
    #pragma unroll
    for (int i = 0; i < 8; ++i)
        #pragma unroll
        for (int j = 0; j < 8; ++j) acc[i][j] = 0.0f;

    for (int kk = 0; kk < CH; kk += BK) {
        // stage W panel: 16x128 floats = 512 float4, 2 iterations
        #pragma unroll
        for (int i = 0; i < 2; ++i) {
            int f4 = i * 256 + tid;
            int k = f4 >> 5;
            int c4 = (f4 & 31) * 4;
            *reinterpret_cast<float4*>(&Wp[k][c4]) =
                *reinterpret_cast<const float4*>(&W[(kk + k) * CH + c4]);
        }
        // stage A panel transposed: 128 rows x 16 k = 512 groups of 4
        #pragma unroll
        for (int i = 0; i < 2; ++i) {
            int f4 = i * 256 + tid;
            int r = f4 >> 2;
            int kp = (f4 & 3) * 4;
            int grow = row0 + r;
            float a0 = 0.f, a1 = 0.f, a2 = 0.f, a3 = 0.f;
            if (grow < M) {
                if constexpr (sizeof(TA) == 4) {
                    float4 a4 = *reinterpret_cast<const float4*>(&A[(size_t)grow * CH + kk + kp]);
                    a0 = a4.x; a1 = a4.y; a2 = a4.z; a3 = a4.w;
                } else {
                    float2 raw = *reinterpret_cast<const float2*>(&A[(size_t)grow * CH + kk + kp]);
                    const __half* hp = reinterpret_cast<const __half*>(&raw);
                    a0 = __half2float(hp[0]); a1 = __half2float(hp[1]);
                    a2 = __half2float(hp[2]); a3 = __half2float(hp[3]);
                }
            }
            At[kp + 0][r] = a0;
            At[kp + 1][r] = a1;
            At[kp + 2][r] = a2;
            At[kp + 3][r] = a3;
        }
        __syncthreads();
        #pragma unroll 4
        for (int k = 0; k < BK; ++k) {
            float a[8], w[8];
            *reinterpret_cast<float4*>(&a[0]) = *reinterpret_cast<const float4*>(&At[k][tr]);
            *reinterpret_cast<float4*>(&a[4]) = *reinterpret_cast<const float4*>(&At[k][tr + 4]);
            *reinterpret_cast<float4*>(&w[0]) = *reinterpret_cast<const float4*>(&Wp[k][tc]);
            *reinterpret_cast<float4*>(&w[4]) = *reinterpret_cast<const float4*>(&Wp[k][tc + 4]);
            #pragma unroll
            for (int i = 0; i < 8; ++i)
                #pragma unroll
                for (int j = 0; j < 8; ++j)
                    acc[i][j] = fmaf(a[i], w[j], acc[i][j]);
        }
        __syncthreads();
    }
    #pragma unroll
    for (int i = 0; i < 8; ++i) {
        int grow = row0 + tr + i;
        if (grow < M) {
            __half hb[8];
            #pragma unroll
            for (int j = 0; j < 8; ++j) hb[j] = __float2half(acc[i][j]);
            *reinterpret_cast<float4*>(&C[(size_t)grow * CH + tc]) =
                *reinterpret_cast<float4*>(hb);
        }
    }
}

__global__ __launch_bounds__(256, 4) void gemm_h_kernel(const __half* __restrict__ A,
                                                        const float* __restrict__ W,
                                                        __half* __restrict__ C, int M) {
    gemm_tile_body<__half>(A, W, C, M, blockIdx.x);
}

// fused: layer-1 GEMM (f32 A) overlapped with the edge-rank atomic pass
#define FUSE_NB 7032  // 782 gemm blocks + 6250 rank blocks

__global__ __launch_bounds__(256, 4) void gemm_rank_kernel(const float* __restrict__ A,
                                                           const float* __restrict__ W,
                                                           __half* __restrict__ C, int M,
                                                           const int* __restrict__ ei,
                                                           int* __restrict__ cnt,
                                                           int* __restrict__ rankv) {
    int bid = blockIdx.x;
    if (bid % 9 == 0) {
        gemm_tile_body<float>(A, W, C, M, bid / 9);
    } else {
        int r = bid - 1 - bid / 9;          // rank-block index 0..6249
        int e = r * 256 + threadIdx.x;      // exact: 6250*256 == NE
        int col = ei[NE + e];
        rankv[e] = atomicAdd(&cnt[col], 1);
    }
}

// ---------------------------------------------------------------------------
// aggregation: QUARTER-wave (16 lanes) per node, dwordx4 (8 fp16 ch/lane)
// covers the 256B row; unroll-2 => 8 independent gather streams per wave.
// Per-channel fmaf order identical to the half-wave version (bit-identical).
// 16 nodes per 256-thread block.
__global__ __launch_bounds__(256) void agg_kernel(const __half* __restrict__ hW,
                                                  const int* __restrict__ colptr,
                                                  const int2* __restrict__ csr,
                                                  const float* __restrict__ selfw,
                                                  const float* __restrict__ bias,
                                                  __half* __restrict__ out) {
    const int q = threadIdx.x >> 4;
    const int l = threadIdx.x & 15;
    const int node = blockIdx.x * 16 + q;      // grid = NN/16 exact
    const int c0 = l * 8;

    float a[8];
    {
        const float sw = selfw[node];
        float4 raw = *reinterpret_cast<const float4*>(&hW[(size_t)node * CH + c0]);
        const __half* sp = reinterpret_cast<const __half*>(&raw);
        #pragma unroll
        for (int j = 0; j < 8; ++j) a[j] = sw * __half2float(sp[j]);
    }

    int e = colptr[node];
    const int e1 = colptr[node + 1];
    for (; e + 1 < e1; e += 2) {
        int2 p0 = csr[e];
        int2 p1 = csr[e + 1];
        float4 r0 = *reinterpret_cast<const float4*>(&hW[(size_t)p0.x * CH + c0]);
        float4 r1 = *reinterpret_cast<const float4*>(&hW[(size_t)p1.x * CH + c0]);
        float v0 = __int_as_float(p0.y);
        float v1 = __int_as_float(p1.y);
        const __half* h0 = reinterpret_cast<const __half*>(&r0);
        const __half* h1 = reinterpret_cast<const __half*>(&r1);
        #pragma unroll
        for (int j = 0; j < 8; ++j) a[j] = fmaf(v0, __half2float(h0[j]), a[j]);
        #pragma unroll
        for (int j = 0; j < 8; ++j) a[j] = fmaf(v1, __half2float(h1[j]), a[j]);
    }
    if (e < e1) {
        int2 p0 = csr[e];
        float4 r0 = *reinterpret_cast<const float4*>(&hW[(size_t)p0.x * CH + c0]);
        float v0 = __int_as_float(p0.y);
        const __half* h0 = reinterpret_cast<const __half*>(&r0);
        #pragma unroll
        for (int j = 0; j < 8; ++j) a[j] = fmaf(v0, __half2float(h0[j]), a[j]);
    }
    const float4 b0 = *reinterpret_cast<const float4*>(&bias[c0]);
    const float4 b1 = *reinterpret_cast<const float4*>(&bias[c0 + 4]);
    __half o[8];
    o[0] = __float2half(fmaxf(a[0] + b0.x, 0.0f));
    o[1] = __float2half(fmaxf(a[1] + b0.y, 0.0f));
    o[2] = __float2half(fmaxf(a[2] + b0.z, 0.0f));
    o[3] = __float2half(fmaxf(a[3] + b0.w, 0.0f));
    o[4] = __float2half(fmaxf(a[4] + b1.x, 0.0f));
    o[5] = __float2half(fmaxf(a[5] + b1.y, 0.0f));
    o[6] = __float2half(fmaxf(a[6] + b1.z, 0.0f));
    o[7] = __float2half(fmaxf(a[7] + b1.w, 0.0f));
    *reinterpret_cast<float4*>(&out[(size_t)node * CH + c0]) = *reinterpret_cast<float4*>(o);
}

// ---------------------------------------------------------------------------
// mean pool per graph (fp16 feat -> f32 accumulate)
__global__ __launch_bounds__(128) void pool_kernel(const __half* __restrict__ feat,
                                                   const int* __restrict__ starts,
                                                   float* __restrict__ pooled) {
    int g = blockIdx.x;
    int c = threadIdx.x;
    int s = starts[g], e = starts[g + 1];
    float acc = 0.0f;
    for (int n = s; n < e; ++n) acc += __half2float(feat[(size_t)n * CH + c]);
    pooled[g * CH + c] = acc / fmaxf((float)(e - s), 1.0f);
}

// final FC
__global__ __launch_bounds__(192) void fc_kernel(const float* __restrict__ pooled,
                                                 const float* __restrict__ fcW,
                                                 const float* __restrict__ fcb,
                                                 float* __restrict__ out) {
    int g = blockIdx.x * 16 + threadIdx.x / 12;
    int o = threadIdx.x % 12;
    if (g >= NG || o >= OUTC) return;
    float acc = fcb[o];
    #pragma unroll 8
    for (int c = 0; c < CH; ++c)
        acc = fmaf(pooled[g * CH + c], fcW[c * OUTC + o], acc);
    out[g * OUTC + o] = acc;
}

// ---------------------------------------------------------------------------
extern "C" void kernel_launch(void* const* d_in, const int* in_sizes, int n_in,
                              void* d_out, int out_size, void* d_ws, size_t ws_size,
                              hipStream_t stream) {
    const float* x      = (const float*)d_in[0];
    const int*   ei     = (const int*)d_in[1];
    const int*   batch  = (const int*)d_in[2];
    const float* ew     = (const float*)d_in[3];
    const float* W1     = (const float*)d_in[4];
    const float* b1     = (const float*)d_in[5];
    const float* W2     = (const float*)d_in[6];
    const float* b2     = (const float*)d_in[7];
    const float* W3     = (const float*)d_in[8];
    const float* b3     = (const float*)d_in[9];
    const float* fcW    = (const float*)d_in[10];
    const float* fcb    = (const float*)d_in[11];
    float* out = (float*)d_out;

    char* p = (char*)d_ws;
    auto alloc = [&](size_t bytes) {
        void* r = (void*)p;
        p += (bytes + 255) & ~(size_t)255;
        return r;
    };
    __half* featA  = (__half*)alloc((size_t)NN * CH * 2);
    __half* featB  = (__half*)alloc((size_t)NN * CH * 2);
    int*   cnt     = (int*)alloc(NN * 4);
    int*   rankv   = (int*)alloc((size_t)NE * 4);
    int*   excl    = (int*)alloc(NN * 4);
    int*   bsum    = (int*)alloc(SCAN_NB * 4);
    int*   boff    = (int*)alloc(SCAN_NB * 4);
    int*   colptr  = (int*)alloc((NN + 1) * 4);
    int2*  csr     = (int2*)alloc((size_t)NE * 8);
    float* dis     = (float*)alloc(NN * 4);
    float* selfw   = (float*)alloc(NN * 4);
    int*   starts  = (int*)alloc((NG + 1) * 4);
    float* pooled  = (float*)alloc((size_t)NG * CH * 4);

    const int nb_nodes = (NN + 255) / 256;      // 391
    const int nb_edges = (NE + 255) / 256;      // 6250
    const int nb_gemm  = (NN + BM - 1) / BM;    // 782
    const int nb_agg   = NN / 16;               // 6250

    // preprocessing (reused by all 3 layers); gemm1 overlapped with rank pass
    init_kernel<<<nb_nodes, 256, 0, stream>>>(cnt);
    gemm_rank_kernel<<<FUSE_NB, 256, 0, stream>>>(x, W1, featA, NN, ei, cnt, rankv);
    scan1_kernel<<<SCAN_NB, 256, 0, stream>>>(cnt, excl, bsum);
    scan2_kernel<<<1, 512, 0, stream>>>(bsum, boff);
    scan3_kernel<<<nb_nodes, 256, 0, stream>>>(excl, boff, colptr);
    scatter_kernel<<<nb_edges, 256, 0, stream>>>(ei, ew, colptr, rankv, csr);
    deg_dis_kernel<<<nb_nodes, 256, 0, stream>>>(colptr, csr, dis, selfw);
    val_kernel<<<nb_nodes, 256, 0, stream>>>(colptr, dis, csr);
    starts_kernel<<<3, 256, 0, stream>>>(batch, starts);

    // layer 1 aggregation (gemm1 already done in fused kernel)
    agg_kernel<<<nb_agg, 256, 0, stream>>>(featA, colptr, csr, selfw, b1, featB);
    // layer 2
    gemm_h_kernel<<<nb_gemm, 256, 0, stream>>>(featB, W2, featA, NN);
    agg_kernel<<<nb_agg, 256, 0, stream>>>(featA, colptr, csr, selfw, b2, featB);
    // layer 3
    gemm_h_kernel<<<nb_gemm, 256, 0, stream>>>(featB, W3, featA, NN);
    agg_kernel<<<nb_agg, 256, 0, stream>>>(featA, colptr, csr, selfw, b3, featB);

    // pool + fc
    pool_kernel<<<NG, 128, 0, stream>>>(featB, starts, pooled);
    fc_kernel<<<(NG + 15) / 16, 192, 0, stream>>>(pooled, fcW, fcb, out);
}

// Round 15
// 626.623 us; speedup vs baseline: 1.5216x; 1.0476x over previous
//
#include <hip/hip_runtime.h>
#include <hip/hip_fp16.h>

#define NN 100000
#define NE 1600000
#define CH 128
#define NG 512
#define OUTC 11

// ---------------------------------------------------------------------------
__global__ void init_kernel(int* __restrict__ cnt) {
    int i = blockIdx.x * 256 + threadIdx.x;
    if (i < NN) cnt[i] = 0;
}

// ---- exclusive scan of cnt[NN] -> colptr[NN+1] (3-kernel hierarchical) ----
__global__ void scan1_kernel(const int* __restrict__ cnt, int* __restrict__ excl,
                             int* __restrict__ bsum) {
    __shared__ int s[256];
    int t = threadIdx.x;
    int i = blockIdx.x * 256 + t;
    int v = (i < NN) ? cnt[i] : 0;
    s[t] = v;
    __syncthreads();
    #pragma unroll
    for (int off = 1; off < 256; off <<= 1) {
        int x = (t >= off) ? s[t - off] : 0;
        __syncthreads();
        s[t] += x;
        __syncthreads();
    }
    if (i < NN) excl[i] = s[t] - v;
    if (t == 255) bsum[blockIdx.x] = s[255];
}

#define SCAN_NB 391  // ceil(100000/256)

__global__ void scan2_kernel(const int* __restrict__ bsum, int* __restrict__ boff) {
    __shared__ int s[512];
    int t = threadIdx.x;
    int v = (t < SCAN_NB) ? bsum[t] : 0;
    s[t] = v;
    __syncthreads();
    #pragma unroll
    for (int off = 1; off < 512; off <<= 1) {
        int x = (t >= off) ? s[t - off] : 0;
        __syncthreads();
        s[t] += x;
        __syncthreads();
    }
    if (t < SCAN_NB) boff[t] = s[t] - v;
}

__global__ void scan3_kernel(const int* __restrict__ excl, const int* __restrict__ boff,
                             int* __restrict__ colptr) {
    int i = blockIdx.x * 256 + threadIdx.x;
    if (i < NN) colptr[i] = excl[i] + boff[i >> 8];
    if (i == 0) colptr[NN] = NE;
}

// scatter (atomic-free): csr[pos] = {src row, raw edge weight}
__global__ void scatter_kernel(const int* __restrict__ ei, const float* __restrict__ ew,
                               const int* __restrict__ colptr, const int* __restrict__ rankv,
                               int2* __restrict__ csr) {
    int e = blockIdx.x * 256 + threadIdx.x;
    int row = ei[e];
    int col = ei[NE + e];
    int pos = colptr[col] + rankv[e];
    csr[pos] = make_int2(row, __float_as_int(ew[e]));
}

// per-node: deg = segment sum of ew; dis = 1/sqrt(deg+1)  (f32 exact)
__global__ void deg_dis_kernel(const int* __restrict__ colptr, const int2* __restrict__ csr,
                               float* __restrict__ dis, float* __restrict__ selfw) {
    int i = blockIdx.x * 256 + threadIdx.x;
    if (i >= NN) return;
    int s = colptr[i], t = colptr[i + 1];
    float sum = 0.0f;
    for (int p = s; p < t; ++p) sum += __int_as_float(csr[p].y);
    float d = sum + 1.0f;
    float r = 1.0f / sqrtf(d);
    dis[i] = r;
    selfw[i] = r * r;
}

// per-node: csr[p].y <- dis[row] * ew * dis[col]
__global__ void val_kernel(const int* __restrict__ colptr, const float* __restrict__ dis,
                           int2* __restrict__ csr) {
    int i = blockIdx.x * 256 + threadIdx.x;
    if (i >= NN) return;
    float dn = dis[i];
    int s = colptr[i], t = colptr[i + 1];
    for (int p = s; p < t; ++p) {
        int2 v = csr[p];
        csr[p].y = __float_as_int(dis[v.x] * __int_as_float(v.y) * dn);
    }
}

// graph boundaries in sorted batch
__global__ void starts_kernel(const int* __restrict__ batch, int* __restrict__ starts) {
    int g = blockIdx.x * 256 + threadIdx.x;
    if (g > NG) return;
    int lo = 0, hi = NN;
    while (lo < hi) {
        int mid = (lo + hi) >> 1;
        if (batch[mid] < g) lo = mid + 1; else hi = mid;
    }
    starts[g] = lo;
}

// ---------------------------------------------------------------------------
// GEMM: C[M,128](fp16) = A[M,128] @ W[128,128](f32). BM=64 (1563 blocks -> ~6
// blocks/CU in the tail vs 3 at BM=128; round-13 profile showed the gemm tail
// is block-count-starved at 29% occupancy). 256 thr, 4x8 micro-tile, BK=16,
// LDS 12.5KB. Each output's k-chain is still sequential 0..127 ->
// bit-identical to previous rounds.
#define BM 64
#define BK 16

template <typename TA>
__device__ __forceinline__ void gemm_tile_body(const TA* __restrict__ A,
                                               const float* __restrict__ W,
                                               __half* __restrict__ C, int M, int blk) {
    __shared__ float At[BK][68];    // [k][row], +4 pad
    __shared__ float Wp[BK][CH];    // [k][col]
    const int tid = threadIdx.x;
    const int row0 = blk * BM;
    const int tc = (tid & 15) * 8;  // 16 thread-cols x 8
    const int tr = (tid >> 4) * 4;  // 16 thread-rows x 4

    float acc[4][8];
    #pragma unroll
    for (int i = 0; i < 4; ++i)
        #pragma unroll
        for (int j = 0; j < 8; ++j) acc[i][j] = 0.0f;

    for (int kk = 0; kk < CH; kk += BK) {
        // W panel: 16x128 floats = 512 float4, 2 iterations
        #pragma unroll
        for (int i = 0; i < 2; ++i) {
            int f4 = i * 256 + tid;
            int k = f4 >> 5;
            int c4 = (f4 & 31) * 4;
            *reinterpret_cast<float4*>(&Wp[k][c4]) =
                *reinterpret_cast<const float4*>(&W[(kk + k) * CH + c4]);
        }
        // A panel transposed: 64 rows x 16 k = 256 groups of 4, 1 iteration
        {
            int r = tid >> 2;          // 0..63
            int kp = (tid & 3) * 4;    // 0,4,8,12
            int grow = row0 + r;
            float a0 = 0.f, a1 = 0.f, a2 = 0.f, a3 = 0.f;
            if (grow < M) {
                if constexpr (sizeof(TA) == 4) {
                    float4 a4 = *reinterpret_cast<const float4*>(&A[(size_t)grow * CH + kk + kp]);
                    a0 = a4.x; a1 = a4.y; a2 = a4.z; a3 = a4.w;
                } else {
                    float2 raw = *reinterpret_cast<const float2*>(&A[(size_t)grow * CH + kk + kp]);
                    const __half* hp = reinterpret_cast<const __half*>(&raw);
                    a0 = __half2float(hp[0]); a1 = __half2float(hp[1]);
                    a2 = __half2float(hp[2]); a3 = __half2float(hp[3]);
                }
            }
            At[kp + 0][r] = a0;
            At[kp + 1][r] = a1;
            At[kp + 2][r] = a2;
            At[kp + 3][r] = a3;
        }
        __syncthreads();
        #pragma unroll 4
        for (int k = 0; k < BK; ++k) {
            float4 a4 = *reinterpret_cast<const float4*>(&At[k][tr]);
            float w[8];
            *reinterpret_cast<float4*>(&w[0]) = *reinterpret_cast<const float4*>(&Wp[k][tc]);
            *reinterpret_cast<float4*>(&w[4]) = *reinterpret_cast<const float4*>(&Wp[k][tc + 4]);
            float a[4] = {a4.x, a4.y, a4.z, a4.w};
            #pragma unroll
            for (int i = 0; i < 4; ++i)
                #pragma unroll
                for (int j = 0; j < 8; ++j)
                    acc[i][j] = fmaf(a[i], w[j], acc[i][j]);
        }
        __syncthreads();
    }
    #pragma unroll
    for (int i = 0; i < 4; ++i) {
        int grow = row0 + tr + i;
        if (grow < M) {
            __half hb[8];
            #pragma unroll
            for (int j = 0; j < 8; ++j) hb[j] = __float2half(acc[i][j]);
            *reinterpret_cast<float4*>(&C[(size_t)grow * CH + tc]) =
                *reinterpret_cast<float4*>(hb);
        }
    }
}

#define NB_GEMM 1563  // ceil(100000/64)

__global__ __launch_bounds__(256, 4) void gemm_h_kernel(const __half* __restrict__ A,
                                                        const float* __restrict__ W,
                                                        __half* __restrict__ C, int M) {
    gemm_tile_body<__half>(A, W, C, M, blockIdx.x);
}

// fused: layer-1 GEMM (f32 A, every 5th block) + edge-rank atomic pass
#define FUSE_NB 7813  // 1563 gemm + 6250 rank

__global__ __launch_bounds__(256, 4) void gemm_rank_kernel(const float* __restrict__ A,
                                                           const float* __restrict__ W,
                                                           __half* __restrict__ C, int M,
                                                           const int* __restrict__ ei,
                                                           int* __restrict__ cnt,
                                                           int* __restrict__ rankv) {
    int bid = blockIdx.x;
    if (bid % 5 == 0) {
        gemm_tile_body<float>(A, W, C, M, bid / 5);
    } else {
        int r = bid - 1 - bid / 5;          // rank-block index 0..6249
        int e = r * 256 + threadIdx.x;      // exact: 6250*256 == NE
        int col = ei[NE + e];
        rankv[e] = atomicAdd(&cnt[col], 1);
    }
}

// ---------------------------------------------------------------------------
// aggregation: QUARTER-wave (16 lanes) per node, dwordx4 (8 fp16 ch/lane);
// unroll-4 => 4 independent 256B gathers + 4 csr reads in flight per iter
// (round-13: fp16 halved FETCH but time fell only ~20% -> latency-bound).
// fmaf applied in edge order -> bit-identical accumulation.
__global__ __launch_bounds__(256) void agg_kernel(const __half* __restrict__ hW,
                                                  const int* __restrict__ colptr,
                                                  const int2* __restrict__ csr,
                                                  const float* __restrict__ selfw,
                                                  const float* __restrict__ bias,
                                                  __half* __restrict__ out) {
    const int q = threadIdx.x >> 4;
    const int l = threadIdx.x & 15;
    const int node = blockIdx.x * 16 + q;      // grid = NN/16 exact
    const int c0 = l * 8;

    float a[8];
    {
        const float sw = selfw[node];
        float4 raw = *reinterpret_cast<const float4*>(&hW[(size_t)node * CH + c0]);
        const __half* sp = reinterpret_cast<const __half*>(&raw);
        #pragma unroll
        for (int j = 0; j < 8; ++j) a[j] = sw * __half2float(sp[j]);
    }

    int e = colptr[node];
    const int e1 = colptr[node + 1];
    for (; e + 3 < e1; e += 4) {
        int2 p0 = csr[e];
        int2 p1 = csr[e + 1];
        int2 p2 = csr[e + 2];
        int2 p3 = csr[e + 3];
        float4 r0 = *reinterpret_cast<const float4*>(&hW[(size_t)p0.x * CH + c0]);
        float4 r1 = *reinterpret_cast<const float4*>(&hW[(size_t)p1.x * CH + c0]);
        float4 r2 = *reinterpret_cast<const float4*>(&hW[(size_t)p2.x * CH + c0]);
        float4 r3 = *reinterpret_cast<const float4*>(&hW[(size_t)p3.x * CH + c0]);
        float v0 = __int_as_float(p0.y);
        float v1 = __int_as_float(p1.y);
        float v2 = __int_as_float(p2.y);
        float v3 = __int_as_float(p3.y);
        const __half* h0 = reinterpret_cast<const __half*>(&r0);
        const __half* h1 = reinterpret_cast<const __half*>(&r1);
        const __half* h2 = reinterpret_cast<const __half*>(&r2);
        const __half* h3 = reinterpret_cast<const __half*>(&r3);
        #pragma unroll
        for (int j = 0; j < 8; ++j) a[j] = fmaf(v0, __half2float(h0[j]), a[j]);
        #pragma unroll
        for (int j = 0; j < 8; ++j) a[j] = fmaf(v1, __half2float(h1[j]), a[j]);
        #pragma unroll
        for (int j = 0; j < 8; ++j) a[j] = fmaf(v2, __half2float(h2[j]), a[j]);
        #pragma unroll
        for (int j = 0; j < 8; ++j) a[j] = fmaf(v3, __half2float(h3[j]), a[j]);
    }
    for (; e < e1; ++e) {
        int2 p0 = csr[e];
        float4 r0 = *reinterpret_cast<const float4*>(&hW[(size_t)p0.x * CH + c0]);
        float v0 = __int_as_float(p0.y);
        const __half* h0 = reinterpret_cast<const __half*>(&r0);
        #pragma unroll
        for (int j = 0; j < 8; ++j) a[j] = fmaf(v0, __half2float(h0[j]), a[j]);
    }
    const float4 b0 = *reinterpret_cast<const float4*>(&bias[c0]);
    const float4 b1 = *reinterpret_cast<const float4*>(&bias[c0 + 4]);
    __half o[8];
    o[0] = __float2half(fmaxf(a[0] + b0.x, 0.0f));
    o[1] = __float2half(fmaxf(a[1] + b0.y, 0.0f));
    o[2] = __float2half(fmaxf(a[2] + b0.z, 0.0f));
    o[3] = __float2half(fmaxf(a[3] + b0.w, 0.0f));
    o[4] = __float2half(fmaxf(a[4] + b1.x, 0.0f));
    o[5] = __float2half(fmaxf(a[5] + b1.y, 0.0f));
    o[6] = __float2half(fmaxf(a[6] + b1.z, 0.0f));
    o[7] = __float2half(fmaxf(a[7] + b1.w, 0.0f));
    *reinterpret_cast<float4*>(&out[(size_t)node * CH + c0]) = *reinterpret_cast<float4*>(o);
}

// ---------------------------------------------------------------------------
// mean pool per graph (fp16 feat -> f32 accumulate)
__global__ __launch_bounds__(128) void pool_kernel(const __half* __restrict__ feat,
                                                   const int* __restrict__ starts,
                                                   float* __restrict__ pooled) {
    int g = blockIdx.x;
    int c = threadIdx.x;
    int s = starts[g], e = starts[g + 1];
    float acc = 0.0f;
    for (int n = s; n < e; ++n) acc += __half2float(feat[(size_t)n * CH + c]);
    pooled[g * CH + c] = acc / fmaxf((float)(e - s), 1.0f);
}

// final FC
__global__ __launch_bounds__(192) void fc_kernel(const float* __restrict__ pooled,
                                                 const float* __restrict__ fcW,
                                                 const float* __restrict__ fcb,
                                                 float* __restrict__ out) {
    int g = blockIdx.x * 16 + threadIdx.x / 12;
    int o = threadIdx.x % 12;
    if (g >= NG || o >= OUTC) return;
    float acc = fcb[o];
    #pragma unroll 8
    for (int c = 0; c < CH; ++c)
        acc = fmaf(pooled[g * CH + c], fcW[c * OUTC + o], acc);
    out[g * OUTC + o] = acc;
}

// ---------------------------------------------------------------------------
extern "C" void kernel_launch(void* const* d_in, const int* in_sizes, int n_in,
                              void* d_out, int out_size, void* d_ws, size_t ws_size,
                              hipStream_t stream) {
    const float* x      = (const float*)d_in[0];
    const int*   ei     = (const int*)d_in[1];
    const int*   batch  = (const int*)d_in[2];
    const float* ew     = (const float*)d_in[3];
    const float* W1     = (const float*)d_in[4];
    const float* b1     = (const float*)d_in[5];
    const float* W2     = (const float*)d_in[6];
    const float* b2     = (const float*)d_in[7];
    const float* W3     = (const float*)d_in[8];
    const float* b3     = (const float*)d_in[9];
    const float* fcW    = (const float*)d_in[10];
    const float* fcb    = (const float*)d_in[11];
    float* out = (float*)d_out;

    char* p = (char*)d_ws;
    auto alloc = [&](size_t bytes) {
        void* r = (void*)p;
        p += (bytes + 255) & ~(size_t)255;
        return r;
    };
    __half* featA  = (__half*)alloc((size_t)NN * CH * 2);
    __half* featB  = (__half*)alloc((size_t)NN * CH * 2);
    int*   cnt     = (int*)alloc(NN * 4);
    int*   rankv   = (int*)alloc((size_t)NE * 4);
    int*   excl    = (int*)alloc(NN * 4);
    int*   bsum    = (int*)alloc(SCAN_NB * 4);
    int*   boff    = (int*)alloc(SCAN_NB * 4);
    int*   colptr  = (int*)alloc((NN + 1) * 4);
    int2*  csr     = (int2*)alloc((size_t)NE * 8);
    float* dis     = (float*)alloc(NN * 4);
    float* selfw   = (float*)alloc(NN * 4);
    int*   starts  = (int*)alloc((NG + 1) * 4);
    float* pooled  = (float*)alloc((size_t)NG * CH * 4);

    const int nb_nodes = (NN + 255) / 256;      // 391
    const int nb_edges = (NE + 255) / 256;      // 6250
    const int nb_agg   = NN / 16;               // 6250

    // preprocessing (reused by all 3 layers); gemm1 overlapped with rank pass
    init_kernel<<<nb_nodes, 256, 0, stream>>>(cnt);
    gemm_rank_kernel<<<FUSE_NB, 256, 0, stream>>>(x, W1, featA, NN, ei, cnt, rankv);
    scan1_kernel<<<SCAN_NB, 256, 0, stream>>>(cnt, excl, bsum);
    scan2_kernel<<<1, 512, 0, stream>>>(bsum, boff);
    scan3_kernel<<<nb_nodes, 256, 0, stream>>>(excl, boff, colptr);
    scatter_kernel<<<nb_edges, 256, 0, stream>>>(ei, ew, colptr, rankv, csr);
    deg_dis_kernel<<<nb_nodes, 256, 0, stream>>>(colptr, csr, dis, selfw);
    val_kernel<<<nb_nodes, 256, 0, stream>>>(colptr, dis, csr);
    starts_kernel<<<3, 256, 0, stream>>>(batch, starts);

    // layer 1 aggregation (gemm1 already done in fused kernel)
    agg_kernel<<<nb_agg, 256, 0, stream>>>(featA, colptr, csr, selfw, b1, featB);
    // layer 2
    gemm_h_kernel<<<NB_GEMM, 256, 0, stream>>>(featB, W2, featA, NN);
    agg_kernel<<<nb_agg, 256, 0, stream>>>(featA, colptr, csr, selfw, b2, featB);
    // layer 3
    gemm_h_kernel<<<NB_GEMM, 256, 0, stream>>>(featB, W3, featA, NN);
    agg_kernel<<<nb_agg, 256, 0, stream>>>(featA, colptr, csr, selfw, b3, featB);

    // pool + fc
    pool_kernel<<<NG, 128, 0, stream>>>(featB, starts, pooled);
    fc_kernel<<<(NG + 15) / 16, 192, 0, stream>>>(pooled, fcW, fcb, out);
}